// Round 17
// baseline (177.851 us; speedup 1.0000x reference)
//
#include <hip/hip_runtime.h>
#include <math.h>

#define Bb 8
#define Vv 3
#define Ss 1200
#define SgP 1280                 // padded gvec row length
#define Ff 16
#define Hh 32
#define Kk 10
#define STEPS 12
#define ROWS (Bb*Vv*Ss)          // 28800
#define L (Vv*Ss)                // 3600
#define KPAD 1280                // 4 waves * 320
#define NKB 160                  // KPAD/8 k-blocks

typedef __attribute__((ext_vector_type(8))) short bf16x8;
typedef __attribute__((ext_vector_type(4))) float f32x4;
typedef __attribute__((ext_vector_type(4))) unsigned int u32x4;

__device__ __forceinline__ unsigned int pack_hi2(float x0, float x1) {
    return (__float_as_uint(x1) & 0xFFFF0000u) | (__float_as_uint(x0) >> 16);
}
__device__ __forceinline__ unsigned int pack_lo2(float x0, float x1) {
    float h0 = __uint_as_float(__float_as_uint(x0) & 0xFFFF0000u);
    float h1 = __uint_as_float(__float_as_uint(x1) & 0xFFFF0000u);
    return (__float_as_uint(x1 - h1) & 0xFFFF0000u) | (__float_as_uint(x0 - h0) >> 16);
}
// monotone float<->uint for atomicMax
__device__ __forceinline__ unsigned int enc_f(float f) {
    unsigned int u = __float_as_uint(f);
    return (u >> 31) ? ~u : (u | 0x80000000u);
}
__device__ __forceinline__ float dec_f(unsigned int e) {
    return (e >> 31) ? __uint_as_float(e & 0x7FFFFFFFu) : __uint_as_float(~e);
}

// ---------------- Kernel A: fused Wh compute + transpose-split + Gmax atomic ------------
__global__ __launch_bounds__(256) void wh_wht_k(const float* __restrict__ feat,
                                                const float* __restrict__ W_gat,
                                                const float* __restrict__ a_gat,
                                                ushort* __restrict__ WhT,
                                                float* __restrict__ fvec,
                                                float* __restrict__ gvecP,
                                                unsigned int* __restrict__ GmaxE) {
    int bv = blockIdx.x / 20, t = blockIdx.x % 20;
    int b = bv / Vv, v = bv - b * Vv;
    int s0 = t * 64;
    int tid = threadIdx.x;

    __shared__ float T[64][33];
    __shared__ float Wg[16][32];
    __shared__ float gred[8];
    for (int i = tid; i < 512; i += 256) Wg[i >> 5][i & 31] = W_gat[v * 512 + i];
    __syncthreads();

    int r8 = tid >> 5, h = tid & 31;
    float a1 = a_gat[v * 64 + h];
    float a2 = a_gat[v * 64 + 32 + h];
    float myg = -3.0e38f;
#pragma unroll
    for (int pass = 0; pass < 8; ++pass) {
        int s = s0 + pass * 8 + r8;
        float acc = 0.f;
        if (s < Ss) {
            const float4* fe = (const float4*)(feat + ((size_t)b * Ss + s) * Ff);
            float4 f0 = fe[0], f1 = fe[1], f2 = fe[2], f3 = fe[3];
            acc += f0.x * Wg[0][h]  + f0.y * Wg[1][h]  + f0.z * Wg[2][h]  + f0.w * Wg[3][h];
            acc += f1.x * Wg[4][h]  + f1.y * Wg[5][h]  + f1.z * Wg[6][h]  + f1.w * Wg[7][h];
            acc += f2.x * Wg[8][h]  + f2.y * Wg[9][h]  + f2.z * Wg[10][h] + f2.w * Wg[11][h];
            acc += f3.x * Wg[12][h] + f3.y * Wg[13][h] + f3.z * Wg[14][h] + f3.w * Wg[15][h];
        }
        T[pass * 8 + r8][h] = acc;
        float pf = acc * a1, pg = acc * a2;
#pragma unroll
        for (int m = 16; m >= 1; m >>= 1) {
            pf += __shfl_xor(pf, m);
            pg += __shfl_xor(pg, m);
        }
        if (h == 0) {
            if (s < Ss) { fvec[bv * Ss + s] = pf; myg = fmaxf(myg, pg); }
            gvecP[(size_t)bv * SgP + s] = (s < Ss) ? pg : 0.f;  // pad rows write 0
        }
    }
    if (h == 0) gred[r8] = myg;
    __syncthreads();
    if (tid == 0) {
        float m = gred[0];
#pragma unroll
        for (int i = 1; i < 8; ++i) m = fmaxf(m, gred[i]);
        atomicMax(&GmaxE[bv], enc_f(m));
    }

    int hh = tid >> 3, c = tid & 7;       // 32 h x 8 kb-in-block
    int kb = t * 8 + c;
    unsigned int hb[4], lb[4];
#pragma unroll
    for (int j = 0; j < 4; ++j) {
        float e0 = T[c * 8 + 2 * j][hh], e1 = T[c * 8 + 2 * j + 1][hh];
        hb[j] = pack_hi2(e0, e1);
        lb[j] = pack_lo2(e0, e1);
    }
    size_t base = (((size_t)bv * NKB + kb) * 2) * 256 + hh * 8;   // ushort index
    *(uint4*)(WhT + base)       = make_uint4(hb[0], hb[1], hb[2], hb[3]);  // hi plane
    *(uint4*)(WhT + base + 256) = make_uint4(lb[0], lb[1], lb[2], lb[3]);  // lo plane
}

// ---------------- Kernel B: MFMA GAT attention, direct adj, register burst preload ------
// 4 waves split K; each lane preloads its whole 320-float adj k-window as 20 independent
// float4 (80 VGPR) BEFORE any consumption -> ~20 KB in flight per wave (HBM-stream MLP).
__global__ __launch_bounds__(256, 2) void gat_mfma_k(const float* __restrict__ adj,
                                                     const ushort* __restrict__ WhT,
                                                     const float* __restrict__ fvec,
                                                     const float* __restrict__ gvecP,
                                                     const unsigned int* __restrict__ GmaxE,
                                                     float* __restrict__ hid,
                                                     float* __restrict__ hsel) {
    int blk = blockIdx.x;
    int bv = blk / 75, tb = blk % 75;
    int wk = threadIdx.x >> 6, lane = threadIdx.x & 63;
    int rowbase = tb * 16;
    int lr = lane & 15, kg = lane >> 4;
    int b = bv / Vv, v = bv - b * Vv;

    int ar = rowbase + lr;                // always < 1200
    const float* adj_r = adj + ((size_t)bv * Ss + ar) * Ss;
    const float* g_b = gvecP + (size_t)bv * SgP;
    float fr = fvec[bv * Ss + ar];
    float M = fr + dec_f(GmaxE[bv]);
    float Mr = fmaxf(M, 0.2f * M);        // leaky_relu of bound >= true row max

    const float4 z4 = make_float4(0.f, 0.f, 0.f, 0.f);
    int kst = wk * 320;

    // ---- burst preload: 20 independent float4 of adj (lane's whole k-window) ----
    float4 av[20];
#pragma unroll
    for (int s = 0; s < 10; ++s) {
        int t0 = kst + s * 32 + kg * 8;   // multiple of 8; <= 1272
        bool ok = (t0 + 8 <= Ss);
        av[2 * s]     = ok ? *(const float4*)(adj_r + t0)     : z4;
        av[2 * s + 1] = ok ? *(const float4*)(adj_r + t0 + 4) : z4;
    }

    f32x4 acc0 = {0.f, 0.f, 0.f, 0.f}, acc1 = {0.f, 0.f, 0.f, 0.f};
    float psum = 0.f;
    const ushort* Wbv = WhT + ((size_t)bv * NKB) * 512;

#pragma unroll
    for (int s = 0; s < 10; ++s) {
        int t0 = kst + s * 32 + kg * 8;   // <= 1272; WhT/gvecP padded to 1280
        int kb = t0 >> 3;

        const ushort* Bp = Wbv + (size_t)kb * 512 + lr * 8;
        bf16x8 bh0 = *(const bf16x8*)(Bp);            // hi, h = lr
        bf16x8 bh1 = *(const bf16x8*)(Bp + 128);      // hi, h = 16+lr
        bf16x8 bl0 = *(const bf16x8*)(Bp + 256);      // lo, h = lr
        bf16x8 bl1 = *(const bf16x8*)(Bp + 384);      // lo, h = 16+lr

        float4 gA = *(const float4*)(g_b + t0);
        float4 gB = *(const float4*)(g_b + t0 + 4);
        float gv8[8] = {gA.x, gA.y, gA.z, gA.w, gB.x, gB.y, gB.z, gB.w};
        float aw8[8] = {av[2*s].x, av[2*s].y, av[2*s].z, av[2*s].w,
                        av[2*s+1].x, av[2*s+1].y, av[2*s+1].z, av[2*s+1].w};
        float p[8];
#pragma unroll
        for (int j = 0; j < 8; ++j) {
            float e = fr + gv8[j];
            e = fmaxf(e, 0.2f * e);
            float pe = __expf(e - Mr);
            p[j] = (aw8[j] > 0.f) ? pe : 0.f;
            psum += p[j];
        }
        unsigned int hbp[4], lbp[4];
#pragma unroll
        for (int j = 0; j < 4; ++j) {
            hbp[j] = pack_hi2(p[2 * j], p[2 * j + 1]);
            lbp[j] = pack_lo2(p[2 * j], p[2 * j + 1]);
        }
        bf16x8 ah = __builtin_bit_cast(bf16x8, (u32x4){hbp[0], hbp[1], hbp[2], hbp[3]});
        bf16x8 al = __builtin_bit_cast(bf16x8, (u32x4){lbp[0], lbp[1], lbp[2], lbp[3]});
        acc0 = __builtin_amdgcn_mfma_f32_16x16x32_bf16(ah, bh0, acc0, 0, 0, 0);
        acc0 = __builtin_amdgcn_mfma_f32_16x16x32_bf16(ah, bl0, acc0, 0, 0, 0);
        acc0 = __builtin_amdgcn_mfma_f32_16x16x32_bf16(al, bh0, acc0, 0, 0, 0);
        acc1 = __builtin_amdgcn_mfma_f32_16x16x32_bf16(ah, bh1, acc1, 0, 0, 0);
        acc1 = __builtin_amdgcn_mfma_f32_16x16x32_bf16(ah, bl1, acc1, 0, 0, 0);
        acc1 = __builtin_amdgcn_mfma_f32_16x16x32_bf16(al, bh1, acc1, 0, 0, 0);
    }

    psum += __shfl_xor(psum, 16);
    psum += __shfl_xor(psum, 32);

    __shared__ float accS[4][2][16][17];
    __shared__ float psS[4][16];
#pragma unroll
    for (int j = 0; j < 4; ++j) {
        accS[wk][0][kg * 4 + j][lr] = acc0[j];
        accS[wk][1][kg * 4 + j][lr] = acc1[j];
    }
    if (lane < 16) psS[wk][lr] = psum;
    __syncthreads();
    if (threadIdx.x < 16)
        psS[0][threadIdx.x] += psS[1][threadIdx.x] + psS[2][threadIdx.x] + psS[3][threadIdx.x];
    __syncthreads();

    bool qb = (tb == 50);                 // rows 800..815
    for (int idx = threadIdx.x; idx < 512; idx += 256) {
        int r = idx >> 5, col = idx & 31, tt = col >> 4, c = col & 15;
        float a = accS[0][tt][r][c] + accS[1][tt][r][c] + accS[2][tt][r][c] + accS[3][tt][r][c];
        float rr = a / psS[0][r];
        float hv = (rr > 0.f) ? rr : expm1f(rr);
        hid[((size_t)bv * Ss + rowbase + r) * 32 + col] = hv;
        if (qb && r < 11) hsel[(((size_t)b * Vv + v) * 11 + r) * 32 + col] = hv;
    }
}

// ---------------- Kernel Q: per-batch query precompute (q, qt, qc) in hid-space ---------
__global__ __launch_bounds__(256) void attn_q_k(const float* __restrict__ hsel,
                                                const float* __restrict__ qkv_W,
                                                const float* __restrict__ qkv_b,
                                                float* __restrict__ qt,
                                                float* __restrict__ qc) {
    int b = blockIdx.x;
    int tid = threadIdx.x;
    __shared__ float hq[33][33];
    __shared__ float W1[32][33];
    __shared__ float W2[32][33];
    __shared__ float qS[33][33];

    for (int idx = tid; idx < 33 * 32; idx += 256) {
        int q = idx >> 5, i = idx & 31;
        int si = q / 3, v = q - si * 3;
        hq[q][i] = hsel[(((size_t)b * Vv + v) * 11 + si) * 32 + i];
    }
    for (int idx = tid; idx < 1024; idx += 256) {
        int i = idx >> 5, j = idx & 31;
        W1[i][j] = qkv_W[i * 96 + j];
        W2[i][j] = qkv_W[i * 96 + 32 + j];
    }
    __syncthreads();
    for (int idx = tid; idx < 33 * 32; idx += 256) {
        int q = idx >> 5, j = idx & 31;
        float a = qkv_b[j];
#pragma unroll
        for (int i = 0; i < 32; ++i) a += hq[q][i] * W1[i][j];
        qS[q][j] = a;
    }
    __syncthreads();
    for (int idx = tid; idx < 33 * 32; idx += 256) {
        int q = idx >> 5, i = idx & 31;
        float a = 0.f;
#pragma unroll
        for (int j = 0; j < 32; ++j) a += qS[q][j] * W2[i][j];
        qt[(size_t)b * 33 * 32 + q * 32 + i] = a;
    }
    if (tid < 33) {
        float a = 0.f;
        for (int j = 0; j < 32; ++j) a += qS[tid][j] * qkv_b[32 + j];
        qc[b * 33 + tid] = a;
    }
}

// ---------------- Kernel D1: split-K attention partials, hid-space ----------------
#define CH 120
#define NCH 30
#define PREC 34
__global__ __launch_bounds__(256) void attn_part_k(const float* __restrict__ hid,
                                                   const float* __restrict__ qt,
                                                   const float* __restrict__ qc,
                                                   float* __restrict__ part) {
    int blk = blockIdx.x;                 // b*NCH + ch
    int b = blk / NCH, ch = blk % NCH;
    int k0 = ch * CH;
    int tid = threadIdx.x;
    const float inv = 0.1767766952966369f; // 1/sqrt(32)

    __shared__ float hC[CH][33];
    __shared__ float qtS[33][33];
    __shared__ float qcS[33];
    __shared__ float lS[33][124];
    __shared__ float mS[33], lsS[33];

    for (int idx = tid; idx < CH * 32; idx += 256) {
        int r = idx >> 5, i = idx & 31;
        hC[r][i] = hid[((size_t)b * L + k0 + r) * 32 + i];
    }
    for (int idx = tid; idx < 33 * 32; idx += 256) {
        int q = idx >> 5, i = idx & 31;
        qtS[q][i] = qt[(size_t)b * 33 * 32 + q * 32 + i];
    }
    if (tid < 33) qcS[tid] = qc[b * 33 + tid];
    __syncthreads();

    for (int idx = tid; idx < 33 * CH; idx += 256) {
        int q = idx / CH, m = idx - q * CH;
        float d = 0.f;
#pragma unroll
        for (int i = 0; i < 32; ++i) d += qtS[q][i] * hC[m][i];
        lS[q][m] = (d + qcS[q]) * inv;
    }
    __syncthreads();

    int q4 = tid >> 2, j4 = tid & 3;
    if (q4 < 33) {
        float m = -3.0e38f;
        for (int k = j4; k < CH; k += 4) m = fmaxf(m, lS[q4][k]);
        m = fmaxf(m, __shfl_xor(m, 1));
        m = fmaxf(m, __shfl_xor(m, 2));
        float ssum = 0.f;
        for (int k = j4; k < CH; k += 4) {
            float p = __expf(lS[q4][k] - m);
            lS[q4][k] = p;
            ssum += p;
        }
        ssum += __shfl_xor(ssum, 1);
        ssum += __shfl_xor(ssum, 2);
        if (j4 == 0) { mS[q4] = m; lsS[q4] = ssum; }
    }
    __syncthreads();

    float* po = part + ((size_t)b * NCH + ch) * (33 * PREC);
    for (int idx = tid; idx < 33 * 32; idx += 256) {
        int q = idx >> 5, hh = idx & 31;
        float a = 0.f;
        for (int k = 0; k < CH; k += 4) {
            float4 p4 = *(const float4*)&lS[q][k];
            a += p4.x * hC[k][hh] + p4.y * hC[k+1][hh] + p4.z * hC[k+2][hh] + p4.w * hC[k+3][hh];
        }
        po[q * PREC + hh] = a;
    }
    if (tid < 33) { po[tid * PREC + 32] = mS[tid]; po[tid * PREC + 33] = lsS[tid]; }
}

// ---------------- Kernel D2+E: combine + Wv + o-proj + fuse + gate + scores + GRU -------
__global__ __launch_bounds__(256) void comb_head_k(const float* __restrict__ part,
                                                   const float* __restrict__ hsel,
                                                   const float* __restrict__ qkv_W,
                                                   const float* __restrict__ qkv_b,
                                                   const float* __restrict__ o_W,
                                                   const float* __restrict__ o_b,
                                                   const float* __restrict__ fus_W,
                                                   const float* __restrict__ fus_b,
                                                   const float* __restrict__ dis_lab,
                                                   const float* __restrict__ att1_W,
                                                   const float* __restrict__ att1_b,
                                                   const float* __restrict__ att2_W,
                                                   const float* __restrict__ att2_b,
                                                   const float* __restrict__ Wih,
                                                   const float* __restrict__ Whh,
                                                   const float* __restrict__ bih,
                                                   const float* __restrict__ bhh,
                                                   const float* __restrict__ out_W,
                                                   const float* __restrict__ out_b,
                                                   float* __restrict__ out) {
    int b = blockIdx.x;
    int tid = threadIdx.x;
    __shared__ float RS[33][NCH];
    __shared__ float LSs[33];
    __shared__ float oS[33][33];
    __shared__ float vS[33][33];
    __shared__ float hfS[33][33];
    __shared__ float hfgS[33][32];
    __shared__ float lab[11][32];
    __shared__ float a1T[32][68];
    __shared__ float WihT[3][32][36];
    __shared__ float WhhT[3][32][36];
    __shared__ float sc[12];
    __shared__ float xS[32], hS[32];

    const float* pb = part + (size_t)b * NCH * (33 * PREC);

    if (tid < 33) {
        float M = -3.0e38f;
        for (int c = 0; c < NCH; ++c) M = fmaxf(M, pb[c * 33 * PREC + tid * PREC + 32]);
        float Lt = 0.f;
        for (int c = 0; c < NCH; ++c) {
            float w = __expf(pb[c * 33 * PREC + tid * PREC + 32] - M);
            RS[tid][c] = w;
            Lt += w * pb[c * 33 * PREC + tid * PREC + 33];
        }
        LSs[tid] = Lt;
    }
    __syncthreads();

    for (int idx = tid; idx < 33 * 32; idx += 256) {
        int q = idx >> 5, hh = idx & 31;
        float a = 0.f;
        for (int c = 0; c < NCH; ++c) a += RS[q][c] * pb[c * 33 * PREC + q * PREC + hh];
        oS[q][hh] = a / LSs[q];           // sa in hid-space
    }
    __syncthreads();
    for (int idx = tid; idx < 33 * 32; idx += 256) {
        int q = idx >> 5, j = idx & 31;
        float a = qkv_b[64 + j];
#pragma unroll
        for (int i = 0; i < 32; ++i) a += oS[q][i] * qkv_W[i * 96 + 64 + j];
        vS[q][j] = a;                     // sa in v-space
    }
    __syncthreads();
    for (int idx = tid; idx < 33 * 32; idx += 256) {
        int q = idx >> 5, hh = idx & 31;
        int si = q / 3, v = q - si * 3;
        float o = o_b[hh];
#pragma unroll
        for (int i = 0; i < 32; ++i) o += vS[q][i] * o_W[i * 32 + hh];
        float x = hsel[(((size_t)b * Vv + v) * 11 + si) * Hh + hh];
        hfS[q][hh] = 0.8f * o + 0.2f * x;
    }
    __syncthreads();
    for (int idx = tid; idx < 33 * 32; idx += 256) {
        int q = idx >> 5, hh = idx & 31;
        float gacc = fus_b[hh];
#pragma unroll
        for (int i = 0; i < 32; ++i) gacc += hfS[q][i] * fus_W[i * 32 + hh];
        float gate = 1.f / (1.f + __expf(-gacc));
        hfgS[q][hh] = gate * hfS[q][hh];
    }
    __syncthreads();

    // ================= head phase =================
    for (int i = tid; i < 352; i += 256) {
        int k = i >> 5, hh = i & 31;
        lab[k][hh] = hfgS[k * 3 + 0][hh] + hfgS[k * 3 + 1][hh] + hfgS[k * 3 + 2][hh];
    }
    for (int idx = tid; idx < 2048; idx += 256) {
        int i = idx >> 5, jj = idx & 31;
        a1T[jj][i] = att1_W[idx];
    }
    for (int idx = tid; idx < 3072; idx += 256) {
        int i = idx / 96, col = idx - i * 96;
        int g = col >> 5, jj = col & 31;
        WihT[g][jj][i] = Wih[idx];
        WhhT[g][jj][i] = Whh[idx];
    }
    __syncthreads();

    int j = tid & 31, half = (tid >> 5) & 1;
    if (tid < 64) {
        float a2w = att2_W[j];
        float a1b = att1_b[j];
        float a2b = att2_b[0];
#pragma unroll
        for (int kk = 0; kk < 5; ++kk) {
            int k = 2 * kk + half;
            float t1 = a1b;
#pragma unroll
            for (int c = 0; c < 8; ++c) {
                float4 lb4 = *(const float4*)&lab[k][c * 4];
                float4 w4  = *(const float4*)&a1T[j][c * 4];
                t1 += lb4.x * w4.x + lb4.y * w4.y + lb4.z * w4.z + lb4.w * w4.w;
            }
#pragma unroll
            for (int c = 0; c < 8; ++c) {
                float4 lb4 = *(const float4*)&lab[10][c * 4];
                float4 w4  = *(const float4*)&a1T[j][32 + c * 4];
                t1 += lb4.x * w4.x + lb4.y * w4.y + lb4.z * w4.z + lb4.w * w4.w;
            }
            float val = fmaxf(t1, 0.f) * a2w;
#pragma unroll
            for (int mm = 16; mm >= 1; mm >>= 1) val += __shfl_xor(val, mm);
            if (j == 0) sc[k] = (val + a2b) * dis_lab[b * Kk + k];
        }
    }
    __syncthreads();
    if (tid == 0) {
        float mx = sc[0];
        for (int k = 1; k < 10; ++k) mx = fmaxf(mx, sc[k]);
        float sm = 0.f;
        for (int k = 0; k < 10; ++k) { sc[k] = __expf(sc[k] - mx); sm += sc[k]; }
        for (int k = 0; k < 10; ++k) sc[k] /= sm;
    }
    __syncthreads();
    if (tid < 32) {
        float c = 0.f;
        for (int k = 0; k < 10; ++k) c += sc[k] * lab[k][tid];
        xS[tid] = c;
        hS[tid] = lab[10][tid];
    }
    __syncthreads();

    float b_ir = bih[j], b_iz = bih[32 + j], b_in = bih[64 + j];
    float b_hr = bhh[j], b_hz = bhh[32 + j], b_hn = bhh[64 + j];
    float ow = out_W[j], ob = out_b[0];
    int i0 = half * 16;

    for (int t = 0; t < STEPS; ++t) {
        if (tid < 64) {
            float gi_r = 0.f, gi_z = 0.f, gi_n = 0.f;
            float gh_r = 0.f, gh_z = 0.f, gh_n = 0.f;
#pragma unroll
            for (int c = 0; c < 4; ++c) {
                float4 x4 = *(const float4*)&xS[i0 + c * 4];
                float4 h4 = *(const float4*)&hS[i0 + c * 4];
                float4 wr = *(const float4*)&WihT[0][j][i0 + c * 4];
                float4 wz = *(const float4*)&WihT[1][j][i0 + c * 4];
                float4 wn = *(const float4*)&WihT[2][j][i0 + c * 4];
                float4 ur = *(const float4*)&WhhT[0][j][i0 + c * 4];
                float4 uz = *(const float4*)&WhhT[1][j][i0 + c * 4];
                float4 un = *(const float4*)&WhhT[2][j][i0 + c * 4];
                gi_r += x4.x * wr.x + x4.y * wr.y + x4.z * wr.z + x4.w * wr.w;
                gi_z += x4.x * wz.x + x4.y * wz.y + x4.z * wz.z + x4.w * wz.w;
                gi_n += x4.x * wn.x + x4.y * wn.y + x4.z * wn.z + x4.w * wn.w;
                gh_r += h4.x * ur.x + h4.y * ur.y + h4.z * ur.z + h4.w * ur.w;
                gh_z += h4.x * uz.x + h4.y * uz.y + h4.z * uz.z + h4.w * uz.w;
                gh_n += h4.x * un.x + h4.y * un.y + h4.z * un.z + h4.w * un.w;
            }
            gi_r += __shfl_xor(gi_r, 32); gi_z += __shfl_xor(gi_z, 32); gi_n += __shfl_xor(gi_n, 32);
            gh_r += __shfl_xor(gh_r, 32); gh_z += __shfl_xor(gh_z, 32); gh_n += __shfl_xor(gh_n, 32);

            float hprev = hS[j];
            float r = 1.f / (1.f + __expf(-(gi_r + b_ir + gh_r + b_hr)));
            float z = 1.f / (1.f + __expf(-(gi_z + b_iz + gh_z + b_hz)));
            float n = tanhf(gi_n + b_in + r * (gh_n + b_hn));
            float hnew = (1.f - z) * n + z * hprev;

            float outp = hnew * ow;
#pragma unroll
            for (int mm = 16; mm >= 1; mm >>= 1) outp += __shfl_xor(outp, mm);
            if (tid == 0) out[b * STEPS + t] = outp + ob;
            if (tid < 32) oS[0][j] = hnew;     // stash (oS free now)
        }
        __syncthreads();
        if (tid < 32) { hS[tid] = oS[0][tid]; xS[tid] = oS[0][tid]; }
        __syncthreads();
    }
}

// ---------------- launcher ----------------
extern "C" void kernel_launch(void* const* d_in, const int* in_sizes, int n_in,
                              void* d_out, int out_size, void* d_ws, size_t ws_size,
                              hipStream_t stream) {
    const float* feat    = (const float*)d_in[0];
    const float* adj     = (const float*)d_in[1];
    const float* dis_lab = (const float*)d_in[2];
    const float* W_gat   = (const float*)d_in[3];
    const float* a_gat   = (const float*)d_in[4];
    const float* qkv_W   = (const float*)d_in[5];
    const float* qkv_b   = (const float*)d_in[6];
    const float* o_W     = (const float*)d_in[7];
    const float* o_b     = (const float*)d_in[8];
    const float* fus_W   = (const float*)d_in[9];
    const float* fus_b   = (const float*)d_in[10];
    const float* att1_W  = (const float*)d_in[11];
    const float* att1_b  = (const float*)d_in[12];
    const float* att2_W  = (const float*)d_in[13];
    const float* att2_b  = (const float*)d_in[14];
    const float* Wih     = (const float*)d_in[15];
    const float* Whh     = (const float*)d_in[16];
    const float* bih     = (const float*)d_in[17];
    const float* bhh     = (const float*)d_in[18];
    const float* out_W   = (const float*)d_in[19];
    const float* out_b   = (const float*)d_in[20];
    float* out = (float*)d_out;

    float* ws = (float*)d_ws;
    // layout (floats):
    //   hid     @ 0        (921600)  live gat..attn_part
    //   fvec    @ 921600   (28800)
    //   gvecP   @ 950400   (30720 = 24*1280)
    //   GmaxE   @ 981120   (32 u32)
    //   WhT     @ 981152   (983040 fl = 1966080 ush); part (269280) overlays after gat
    //   hsel    @ 1964192  (8448)
    //   qt      @ 1972640  (8448)
    //   qc      @ 1981088  (288)   -> total 1,981,376 fl = 7.9 MB
    float*  hid    = ws;
    float*  fvec   = ws + 921600;
    float*  gvecP  = ws + 950400;
    unsigned int* GmaxE = (unsigned int*)(ws + 981120);
    ushort* WhT    = (ushort*)(ws + 981152);
    float*  part   = ws + 981152;
    float*  hsel   = ws + 1964192;
    float*  qt     = ws + 1972640;
    float*  qc     = ws + 1981088;

    hipMemsetAsync(GmaxE, 0, Bb * Vv * sizeof(unsigned int), stream);
    wh_wht_k<<<dim3(Bb * Vv * 20), dim3(256), 0, stream>>>(feat, W_gat, a_gat,
                                                           WhT, fvec, gvecP, GmaxE);
    gat_mfma_k<<<dim3(Bb * Vv * 75), dim3(256), 0, stream>>>(adj, WhT,
                                                             fvec, gvecP, GmaxE, hid, hsel);
    attn_q_k<<<dim3(Bb), dim3(256), 0, stream>>>(hsel, qkv_W, qkv_b, qt, qc);
    attn_part_k<<<dim3(Bb * NCH), dim3(256), 0, stream>>>(hid, qt, qc, part);
    comb_head_k<<<dim3(Bb), dim3(256), 0, stream>>>(part, hsel, qkv_W, qkv_b,
                                                    o_W, o_b, fus_W, fus_b,
                                                    dis_lab, att1_W, att1_b, att2_W, att2_b,
                                                    Wih, Whh, bih, bhh, out_W, out_b, out);
}

// Round 18
// 124.681 us; speedup vs baseline: 1.4264x; 1.4264x over previous
//
#include <hip/hip_runtime.h>
#include <math.h>

#define Bb 8
#define Vv 3
#define Ss 1200
#define SgP 1280                 // padded gvec row length
#define Ff 16
#define Hh 32
#define Kk 10
#define STEPS 12
#define ROWS (Bb*Vv*Ss)          // 28800
#define L (Vv*Ss)                // 3600
#define KPAD 1280                // 4 waves * 320
#define NKB 160                  // KPAD/8 k-blocks
#define MROW 40                  // mask dwords per row (1280 bits; 38,39 zero)

typedef __attribute__((ext_vector_type(8))) short bf16x8;
typedef __attribute__((ext_vector_type(4))) float f32x4;
typedef __attribute__((ext_vector_type(4))) unsigned int u32x4;

__device__ __forceinline__ unsigned int pack_hi2(float x0, float x1) {
    return (__float_as_uint(x1) & 0xFFFF0000u) | (__float_as_uint(x0) >> 16);
}
__device__ __forceinline__ unsigned int pack_lo2(float x0, float x1) {
    float h0 = __uint_as_float(__float_as_uint(x0) & 0xFFFF0000u);
    float h1 = __uint_as_float(__float_as_uint(x1) & 0xFFFF0000u);
    return (__float_as_uint(x1 - h1) & 0xFFFF0000u) | (__float_as_uint(x0 - h0) >> 16);
}
__device__ __forceinline__ unsigned int spread4(unsigned int x) {
    x = (x | (x << 12)) & 0x000F000Fu;
    x = (x | (x << 6))  & 0x03030303u;
    x = (x | (x << 3))  & 0x11111111u;
    return x;
}
// monotone float<->uint for atomicMax
__device__ __forceinline__ unsigned int enc_f(float f) {
    unsigned int u = __float_as_uint(f);
    return (u >> 31) ? ~u : (u | 0x80000000u);
}
__device__ __forceinline__ float dec_f(unsigned int e) {
    return (e >> 31) ? __uint_as_float(e & 0x7FFFFFFFu) : __uint_as_float(~e);
}

// ---------------- Kernel P: ballot-pack adj -> 1 bit/elem (+ GmaxE init) ---------------
__global__ __launch_bounds__(256) void adj_pack_k(const float* __restrict__ adj,
                                                  unsigned int* __restrict__ maskb,
                                                  unsigned int* __restrict__ GmaxE) {
    if (blockIdx.x == 0 && threadIdx.x < Bb * Vv) GmaxE[threadIdx.x] = 0u;
    int gw = (blockIdx.x * 256 + threadIdx.x) >> 6;   // 0..5759
    int lane = threadIdx.x & 63;
    for (int row = gw; row < ROWS; row += 5760) {
        const float* ar = adj + (size_t)row * Ss;
        unsigned int* mrow = maskb + (size_t)row * MROW;
        float4 a[5];
#pragma unroll
        for (int c = 0; c < 5; ++c) {
            int base = c * 256 + lane * 4;
            a[c] = (base + 3 < Ss) ? *(const float4*)(ar + base)
                                   : make_float4(0.f, 0.f, 0.f, 0.f);
        }
#pragma unroll
        for (int c = 0; c < 5; ++c) {
            unsigned long long b0 = __ballot(a[c].x > 0.f);
            unsigned long long b1 = __ballot(a[c].y > 0.f);
            unsigned long long b2 = __ballot(a[c].z > 0.f);
            unsigned long long b3 = __ballot(a[c].w > 0.f);
            int nw = (c == 4) ? 6 : 8;
            if (lane < nw) {
                int sh = 8 * lane;
                unsigned int B0 = (unsigned int)(b0 >> sh) & 0xFFu;
                unsigned int B1 = (unsigned int)(b1 >> sh) & 0xFFu;
                unsigned int B2 = (unsigned int)(b2 >> sh) & 0xFFu;
                unsigned int B3 = (unsigned int)(b3 >> sh) & 0xFFu;
                mrow[c * 8 + lane] = spread4(B0) | (spread4(B1) << 1)
                                   | (spread4(B2) << 2) | (spread4(B3) << 3);
            }
        }
        if (lane < 2) mrow[38 + lane] = 0u;
    }
}

// ---------------- Kernel A: fused Wh compute + transpose-split + Gmax atomic ------------
__global__ __launch_bounds__(256) void wh_wht_k(const float* __restrict__ feat,
                                                const float* __restrict__ W_gat,
                                                const float* __restrict__ a_gat,
                                                ushort* __restrict__ WhT,
                                                float* __restrict__ fvec,
                                                float* __restrict__ gvecP,
                                                unsigned int* __restrict__ GmaxE) {
    int bv = blockIdx.x / 20, t = blockIdx.x % 20;
    int b = bv / Vv, v = bv - b * Vv;
    int s0 = t * 64;
    int tid = threadIdx.x;

    __shared__ float T[64][33];
    __shared__ float Wg[16][32];
    __shared__ float gred[8];
    for (int i = tid; i < 512; i += 256) Wg[i >> 5][i & 31] = W_gat[v * 512 + i];
    __syncthreads();

    int r8 = tid >> 5, h = tid & 31;
    float a1 = a_gat[v * 64 + h];
    float a2 = a_gat[v * 64 + 32 + h];
    float myg = -3.0e38f;
#pragma unroll
    for (int pass = 0; pass < 8; ++pass) {
        int s = s0 + pass * 8 + r8;
        float acc = 0.f;
        if (s < Ss) {
            const float4* fe = (const float4*)(feat + ((size_t)b * Ss + s) * Ff);
            float4 f0 = fe[0], f1 = fe[1], f2 = fe[2], f3 = fe[3];
            acc += f0.x * Wg[0][h]  + f0.y * Wg[1][h]  + f0.z * Wg[2][h]  + f0.w * Wg[3][h];
            acc += f1.x * Wg[4][h]  + f1.y * Wg[5][h]  + f1.z * Wg[6][h]  + f1.w * Wg[7][h];
            acc += f2.x * Wg[8][h]  + f2.y * Wg[9][h]  + f2.z * Wg[10][h] + f2.w * Wg[11][h];
            acc += f3.x * Wg[12][h] + f3.y * Wg[13][h] + f3.z * Wg[14][h] + f3.w * Wg[15][h];
        }
        T[pass * 8 + r8][h] = acc;
        float pf = acc * a1, pg = acc * a2;
#pragma unroll
        for (int m = 16; m >= 1; m >>= 1) {
            pf += __shfl_xor(pf, m);
            pg += __shfl_xor(pg, m);
        }
        if (h == 0) {
            if (s < Ss) { fvec[bv * Ss + s] = pf; myg = fmaxf(myg, pg); }
            gvecP[(size_t)bv * SgP + s] = (s < Ss) ? pg : 0.f;  // pad rows write 0
        }
    }
    if (h == 0) gred[r8] = myg;
    __syncthreads();
    if (tid == 0) {
        float m = gred[0];
#pragma unroll
        for (int i = 1; i < 8; ++i) m = fmaxf(m, gred[i]);
        atomicMax(&GmaxE[bv], enc_f(m));
    }

    int hh = tid >> 3, c = tid & 7;       // 32 h x 8 kb-in-block
    int kb = t * 8 + c;
    unsigned int hb[4], lb[4];
#pragma unroll
    for (int j = 0; j < 4; ++j) {
        float e0 = T[c * 8 + 2 * j][hh], e1 = T[c * 8 + 2 * j + 1][hh];
        hb[j] = pack_hi2(e0, e1);
        lb[j] = pack_lo2(e0, e1);
    }
    size_t base = (((size_t)bv * NKB + kb) * 2) * 256 + hh * 8;   // ushort index
    *(uint4*)(WhT + base)       = make_uint4(hb[0], hb[1], hb[2], hb[3]);  // hi plane
    *(uint4*)(WhT + base + 256) = make_uint4(lb[0], lb[1], lb[2], lb[3]);  // lo plane
}

// ---------------- Kernel B: MFMA GAT attention, 4-way split-K ----------------
__global__ __launch_bounds__(256, 4) void gat_mfma_k(const unsigned int* __restrict__ maskb,
                                                     const ushort* __restrict__ WhT,
                                                     const float* __restrict__ fvec,
                                                     const float* __restrict__ gvecP,
                                                     const unsigned int* __restrict__ GmaxE,
                                                     float* __restrict__ hid,
                                                     float* __restrict__ hsel) {
    int blk = blockIdx.x;
    int bv = blk / 75, tb = blk % 75;
    int wk = threadIdx.x >> 6, lane = threadIdx.x & 63;
    int rowbase = tb * 16;
    int lr = lane & 15, kg = lane >> 4;
    int b = bv / Vv, v = bv - b * Vv;

    int ar = rowbase + lr;                // always < 1200
    const float* g_b = gvecP + (size_t)bv * SgP;
    float fr = fvec[bv * Ss + ar];
    float M = fr + dec_f(GmaxE[bv]);
    float Mr = fmaxf(M, 0.2f * M);        // leaky_relu of bound >= true row max

    const unsigned int* mrow = maskb + (size_t)(bv * Ss + ar) * MROW + wk * 10;
    unsigned int mw[10];
#pragma unroll
    for (int i = 0; i < 5; ++i) {
        uint2 t = *(const uint2*)(mrow + 2 * i);
        mw[2 * i] = t.x; mw[2 * i + 1] = t.y;
    }

    f32x4 acc0 = {0.f, 0.f, 0.f, 0.f}, acc1 = {0.f, 0.f, 0.f, 0.f};
    float psum = 0.f;
    const ushort* Wbv = WhT + ((size_t)bv * NKB) * 512;

    int kst = wk * 320;
#pragma unroll
    for (int s = 0; s < 10; ++s) {
        int t0 = kst + s * 32 + kg * 8;   // <= 1272; all buffers padded to 1280
        int kb = t0 >> 3;
        unsigned int mb = (mw[s] >> (kg * 8)) & 0xFFu;

        const ushort* Bp = Wbv + (size_t)kb * 512 + lr * 8;
        bf16x8 bh0 = *(const bf16x8*)(Bp);            // hi, h = lr
        bf16x8 bh1 = *(const bf16x8*)(Bp + 128);      // hi, h = 16+lr
        bf16x8 bl0 = *(const bf16x8*)(Bp + 256);      // lo, h = lr
        bf16x8 bl1 = *(const bf16x8*)(Bp + 384);      // lo, h = 16+lr

        float4 gA = *(const float4*)(g_b + t0);
        float4 gB = *(const float4*)(g_b + t0 + 4);
        float gv8[8] = {gA.x, gA.y, gA.z, gA.w, gB.x, gB.y, gB.z, gB.w};
        float p[8];
#pragma unroll
        for (int j = 0; j < 8; ++j) {
            float e = fr + gv8[j];
            e = fmaxf(e, 0.2f * e);
            float pe = __expf(e - Mr);
            p[j] = ((mb >> j) & 1u) ? pe : 0.f;
            psum += p[j];
        }
        unsigned int hbp[4], lbp[4];
#pragma unroll
        for (int j = 0; j < 4; ++j) {
            hbp[j] = pack_hi2(p[2 * j], p[2 * j + 1]);
            lbp[j] = pack_lo2(p[2 * j], p[2 * j + 1]);
        }
        bf16x8 ah = __builtin_bit_cast(bf16x8, (u32x4){hbp[0], hbp[1], hbp[2], hbp[3]});
        bf16x8 al = __builtin_bit_cast(bf16x8, (u32x4){lbp[0], lbp[1], lbp[2], lbp[3]});
        acc0 = __builtin_amdgcn_mfma_f32_16x16x32_bf16(ah, bh0, acc0, 0, 0, 0);
        acc0 = __builtin_amdgcn_mfma_f32_16x16x32_bf16(ah, bl0, acc0, 0, 0, 0);
        acc0 = __builtin_amdgcn_mfma_f32_16x16x32_bf16(al, bh0, acc0, 0, 0, 0);
        acc1 = __builtin_amdgcn_mfma_f32_16x16x32_bf16(ah, bh1, acc1, 0, 0, 0);
        acc1 = __builtin_amdgcn_mfma_f32_16x16x32_bf16(ah, bl1, acc1, 0, 0, 0);
        acc1 = __builtin_amdgcn_mfma_f32_16x16x32_bf16(al, bh1, acc1, 0, 0, 0);
    }

    psum += __shfl_xor(psum, 16);
    psum += __shfl_xor(psum, 32);

    __shared__ float accS[4][2][16][17];
    __shared__ float psS[4][16];
#pragma unroll
    for (int j = 0; j < 4; ++j) {
        accS[wk][0][kg * 4 + j][lr] = acc0[j];
        accS[wk][1][kg * 4 + j][lr] = acc1[j];
    }
    if (lane < 16) psS[wk][lr] = psum;
    __syncthreads();
    if (threadIdx.x < 16)
        psS[0][threadIdx.x] += psS[1][threadIdx.x] + psS[2][threadIdx.x] + psS[3][threadIdx.x];
    __syncthreads();

    bool qb = (tb == 50);                 // rows 800..815
    for (int idx = threadIdx.x; idx < 512; idx += 256) {
        int r = idx >> 5, col = idx & 31, tt = col >> 4, c = col & 15;
        float a = accS[0][tt][r][c] + accS[1][tt][r][c] + accS[2][tt][r][c] + accS[3][tt][r][c];
        float rr = a / psS[0][r];
        float hv = (rr > 0.f) ? rr : expm1f(rr);
        hid[((size_t)bv * Ss + rowbase + r) * 32 + col] = hv;
        if (qb && r < 11) hsel[(((size_t)b * Vv + v) * 11 + r) * 32 + col] = hv;
    }
}

// ---------------- Kernel Q: per-batch query precompute (q, qt, qc) in hid-space ---------
__global__ __launch_bounds__(256) void attn_q_k(const float* __restrict__ hsel,
                                                const float* __restrict__ qkv_W,
                                                const float* __restrict__ qkv_b,
                                                float* __restrict__ qt,
                                                float* __restrict__ qc) {
    int b = blockIdx.x;
    int tid = threadIdx.x;
    __shared__ float hq[33][33];
    __shared__ float W1[32][33];
    __shared__ float W2[32][33];
    __shared__ float qS[33][33];

    for (int idx = tid; idx < 33 * 32; idx += 256) {
        int q = idx >> 5, i = idx & 31;
        int si = q / 3, v = q - si * 3;
        hq[q][i] = hsel[(((size_t)b * Vv + v) * 11 + si) * 32 + i];
    }
    for (int idx = tid; idx < 1024; idx += 256) {
        int i = idx >> 5, j = idx & 31;
        W1[i][j] = qkv_W[i * 96 + j];
        W2[i][j] = qkv_W[i * 96 + 32 + j];
    }
    __syncthreads();
    for (int idx = tid; idx < 33 * 32; idx += 256) {
        int q = idx >> 5, j = idx & 31;
        float a = qkv_b[j];
#pragma unroll
        for (int i = 0; i < 32; ++i) a += hq[q][i] * W1[i][j];
        qS[q][j] = a;
    }
    __syncthreads();
    for (int idx = tid; idx < 33 * 32; idx += 256) {
        int q = idx >> 5, i = idx & 31;
        float a = 0.f;
#pragma unroll
        for (int j = 0; j < 32; ++j) a += qS[q][j] * W2[i][j];
        qt[(size_t)b * 33 * 32 + q * 32 + i] = a;
    }
    if (tid < 33) {
        float a = 0.f;
        for (int j = 0; j < 32; ++j) a += qS[tid][j] * qkv_b[32 + j];
        qc[b * 33 + tid] = a;
    }
}

// ---------------- Kernel D1: split-K attention partials, hid-space ----------------
#define CH 120
#define NCH 30
#define PREC 34
__global__ __launch_bounds__(256) void attn_part_k(const float* __restrict__ hid,
                                                   const float* __restrict__ qt,
                                                   const float* __restrict__ qc,
                                                   float* __restrict__ part) {
    int blk = blockIdx.x;                 // b*NCH + ch
    int b = blk / NCH, ch = blk % NCH;
    int k0 = ch * CH;
    int tid = threadIdx.x;
    const float inv = 0.1767766952966369f; // 1/sqrt(32)

    __shared__ float hC[CH][33];
    __shared__ float qtS[33][33];
    __shared__ float qcS[33];
    __shared__ float lS[33][124];
    __shared__ float mS[33], lsS[33];

    for (int idx = tid; idx < CH * 32; idx += 256) {
        int r = idx >> 5, i = idx & 31;
        hC[r][i] = hid[((size_t)b * L + k0 + r) * 32 + i];
    }
    for (int idx = tid; idx < 33 * 32; idx += 256) {
        int q = idx >> 5, i = idx & 31;
        qtS[q][i] = qt[(size_t)b * 33 * 32 + q * 32 + i];
    }
    if (tid < 33) qcS[tid] = qc[b * 33 + tid];
    __syncthreads();

    for (int idx = tid; idx < 33 * CH; idx += 256) {
        int q = idx / CH, m = idx - q * CH;
        float d = 0.f;
#pragma unroll
        for (int i = 0; i < 32; ++i) d += qtS[q][i] * hC[m][i];
        lS[q][m] = (d + qcS[q]) * inv;
    }
    __syncthreads();

    int q4 = tid >> 2, j4 = tid & 3;
    if (q4 < 33) {
        float m = -3.0e38f;
        for (int k = j4; k < CH; k += 4) m = fmaxf(m, lS[q4][k]);
        m = fmaxf(m, __shfl_xor(m, 1));
        m = fmaxf(m, __shfl_xor(m, 2));
        float ssum = 0.f;
        for (int k = j4; k < CH; k += 4) {
            float p = __expf(lS[q4][k] - m);
            lS[q4][k] = p;
            ssum += p;
        }
        ssum += __shfl_xor(ssum, 1);
        ssum += __shfl_xor(ssum, 2);
        if (j4 == 0) { mS[q4] = m; lsS[q4] = ssum; }
    }
    __syncthreads();

    float* po = part + ((size_t)b * NCH + ch) * (33 * PREC);
    for (int idx = tid; idx < 33 * 32; idx += 256) {
        int q = idx >> 5, hh = idx & 31;
        float a = 0.f;
        for (int k = 0; k < CH; k += 4) {
            float4 p4 = *(const float4*)&lS[q][k];
            a += p4.x * hC[k][hh] + p4.y * hC[k+1][hh] + p4.z * hC[k+2][hh] + p4.w * hC[k+3][hh];
        }
        po[q * PREC + hh] = a;
    }
    if (tid < 33) { po[tid * PREC + 32] = mS[tid]; po[tid * PREC + 33] = lsS[tid]; }
}

// ---------------- Kernel D2+E: combine + Wv + o-proj + fuse + gate + scores + GRU -------
__global__ __launch_bounds__(256) void comb_head_k(const float* __restrict__ part,
                                                   const float* __restrict__ hsel,
                                                   const float* __restrict__ qkv_W,
                                                   const float* __restrict__ qkv_b,
                                                   const float* __restrict__ o_W,
                                                   const float* __restrict__ o_b,
                                                   const float* __restrict__ fus_W,
                                                   const float* __restrict__ fus_b,
                                                   const float* __restrict__ dis_lab,
                                                   const float* __restrict__ att1_W,
                                                   const float* __restrict__ att1_b,
                                                   const float* __restrict__ att2_W,
                                                   const float* __restrict__ att2_b,
                                                   const float* __restrict__ Wih,
                                                   const float* __restrict__ Whh,
                                                   const float* __restrict__ bih,
                                                   const float* __restrict__ bhh,
                                                   const float* __restrict__ out_W,
                                                   const float* __restrict__ out_b,
                                                   float* __restrict__ out) {
    int b = blockIdx.x;
    int tid = threadIdx.x;
    __shared__ float RS[33][NCH];
    __shared__ float LSs[33];
    __shared__ float oS[33][33];
    __shared__ float vS[33][33];
    __shared__ float hfS[33][33];
    __shared__ float hfgS[33][32];
    __shared__ float lab[11][32];
    __shared__ float a1T[32][68];
    __shared__ float WihT[3][32][36];
    __shared__ float WhhT[3][32][36];
    __shared__ float sc[12];
    __shared__ float xS[32], hS[32];

    const float* pb = part + (size_t)b * NCH * (33 * PREC);

    if (tid < 33) {
        float M = -3.0e38f;
        for (int c = 0; c < NCH; ++c) M = fmaxf(M, pb[c * 33 * PREC + tid * PREC + 32]);
        float Lt = 0.f;
        for (int c = 0; c < NCH; ++c) {
            float w = __expf(pb[c * 33 * PREC + tid * PREC + 32] - M);
            RS[tid][c] = w;
            Lt += w * pb[c * 33 * PREC + tid * PREC + 33];
        }
        LSs[tid] = Lt;
    }
    __syncthreads();

    for (int idx = tid; idx < 33 * 32; idx += 256) {
        int q = idx >> 5, hh = idx & 31;
        float a = 0.f;
        for (int c = 0; c < NCH; ++c) a += RS[q][c] * pb[c * 33 * PREC + q * PREC + hh];
        oS[q][hh] = a / LSs[q];           // sa in hid-space
    }
    __syncthreads();
    for (int idx = tid; idx < 33 * 32; idx += 256) {
        int q = idx >> 5, j = idx & 31;
        float a = qkv_b[64 + j];
#pragma unroll
        for (int i = 0; i < 32; ++i) a += oS[q][i] * qkv_W[i * 96 + 64 + j];
        vS[q][j] = a;                     // sa in v-space
    }
    __syncthreads();
    for (int idx = tid; idx < 33 * 32; idx += 256) {
        int q = idx >> 5, hh = idx & 31;
        int si = q / 3, v = q - si * 3;
        float o = o_b[hh];
#pragma unroll
        for (int i = 0; i < 32; ++i) o += vS[q][i] * o_W[i * 32 + hh];
        float x = hsel[(((size_t)b * Vv + v) * 11 + si) * Hh + hh];
        hfS[q][hh] = 0.8f * o + 0.2f * x;
    }
    __syncthreads();
    for (int idx = tid; idx < 33 * 32; idx += 256) {
        int q = idx >> 5, hh = idx & 31;
        float gacc = fus_b[hh];
#pragma unroll
        for (int i = 0; i < 32; ++i) gacc += hfS[q][i] * fus_W[i * 32 + hh];
        float gate = 1.f / (1.f + __expf(-gacc));
        hfgS[q][hh] = gate * hfS[q][hh];
    }
    __syncthreads();

    // ================= head phase =================
    for (int i = tid; i < 352; i += 256) {
        int k = i >> 5, hh = i & 31;
        lab[k][hh] = hfgS[k * 3 + 0][hh] + hfgS[k * 3 + 1][hh] + hfgS[k * 3 + 2][hh];
    }
    for (int idx = tid; idx < 2048; idx += 256) {
        int i = idx >> 5, jj = idx & 31;
        a1T[jj][i] = att1_W[idx];
    }
    for (int idx = tid; idx < 3072; idx += 256) {
        int i = idx / 96, col = idx - i * 96;
        int g = col >> 5, jj = col & 31;
        WihT[g][jj][i] = Wih[idx];
        WhhT[g][jj][i] = Whh[idx];
    }
    __syncthreads();

    int j = tid & 31, half = (tid >> 5) & 1;
    if (tid < 64) {
        float a2w = att2_W[j];
        float a1b = att1_b[j];
        float a2b = att2_b[0];
#pragma unroll
        for (int kk = 0; kk < 5; ++kk) {
            int k = 2 * kk + half;
            float t1 = a1b;
#pragma unroll
            for (int c = 0; c < 8; ++c) {
                float4 lb4 = *(const float4*)&lab[k][c * 4];
                float4 w4  = *(const float4*)&a1T[j][c * 4];
                t1 += lb4.x * w4.x + lb4.y * w4.y + lb4.z * w4.z + lb4.w * w4.w;
            }
#pragma unroll
            for (int c = 0; c < 8; ++c) {
                float4 lb4 = *(const float4*)&lab[10][c * 4];
                float4 w4  = *(const float4*)&a1T[j][32 + c * 4];
                t1 += lb4.x * w4.x + lb4.y * w4.y + lb4.z * w4.z + lb4.w * w4.w;
            }
            float val = fmaxf(t1, 0.f) * a2w;
#pragma unroll
            for (int mm = 16; mm >= 1; mm >>= 1) val += __shfl_xor(val, mm);
            if (j == 0) sc[k] = (val + a2b) * dis_lab[b * Kk + k];
        }
    }
    __syncthreads();
    if (tid == 0) {
        float mx = sc[0];
        for (int k = 1; k < 10; ++k) mx = fmaxf(mx, sc[k]);
        float sm = 0.f;
        for (int k = 0; k < 10; ++k) { sc[k] = __expf(sc[k] - mx); sm += sc[k]; }
        for (int k = 0; k < 10; ++k) sc[k] /= sm;
    }
    __syncthreads();
    if (tid < 32) {
        float c = 0.f;
        for (int k = 0; k < 10; ++k) c += sc[k] * lab[k][tid];
        xS[tid] = c;
        hS[tid] = lab[10][tid];
    }
    __syncthreads();

    float b_ir = bih[j], b_iz = bih[32 + j], b_in = bih[64 + j];
    float b_hr = bhh[j], b_hz = bhh[32 + j], b_hn = bhh[64 + j];
    float ow = out_W[j], ob = out_b[0];
    int i0 = half * 16;

    for (int t = 0; t < STEPS; ++t) {
        if (tid < 64) {
            float gi_r = 0.f, gi_z = 0.f, gi_n = 0.f;
            float gh_r = 0.f, gh_z = 0.f, gh_n = 0.f;
#pragma unroll
            for (int c = 0; c < 4; ++c) {
                float4 x4 = *(const float4*)&xS[i0 + c * 4];
                float4 h4 = *(const float4*)&hS[i0 + c * 4];
                float4 wr = *(const float4*)&WihT[0][j][i0 + c * 4];
                float4 wz = *(const float4*)&WihT[1][j][i0 + c * 4];
                float4 wn = *(const float4*)&WihT[2][j][i0 + c * 4];
                float4 ur = *(const float4*)&WhhT[0][j][i0 + c * 4];
                float4 uz = *(const float4*)&WhhT[1][j][i0 + c * 4];
                float4 un = *(const float4*)&WhhT[2][j][i0 + c * 4];
                gi_r += x4.x * wr.x + x4.y * wr.y + x4.z * wr.z + x4.w * wr.w;
                gi_z += x4.x * wz.x + x4.y * wz.y + x4.z * wz.z + x4.w * wz.w;
                gi_n += x4.x * wn.x + x4.y * wn.y + x4.z * wn.z + x4.w * wn.w;
                gh_r += h4.x * ur.x + h4.y * ur.y + h4.z * ur.z + h4.w * ur.w;
                gh_z += h4.x * uz.x + h4.y * uz.y + h4.z * uz.z + h4.w * uz.w;
                gh_n += h4.x * un.x + h4.y * un.y + h4.z * un.z + h4.w * un.w;
            }
            gi_r += __shfl_xor(gi_r, 32); gi_z += __shfl_xor(gi_z, 32); gi_n += __shfl_xor(gi_n, 32);
            gh_r += __shfl_xor(gh_r, 32); gh_z += __shfl_xor(gh_z, 32); gh_n += __shfl_xor(gh_n, 32);

            float hprev = hS[j];
            float r = 1.f / (1.f + __expf(-(gi_r + b_ir + gh_r + b_hr)));
            float z = 1.f / (1.f + __expf(-(gi_z + b_iz + gh_z + b_hz)));
            float n = tanhf(gi_n + b_in + r * (gh_n + b_hn));
            float hnew = (1.f - z) * n + z * hprev;

            float outp = hnew * ow;
#pragma unroll
            for (int mm = 16; mm >= 1; mm >>= 1) outp += __shfl_xor(outp, mm);
            if (tid == 0) out[b * STEPS + t] = outp + ob;
            if (tid < 32) oS[0][j] = hnew;     // stash (oS free now)
        }
        __syncthreads();
        if (tid < 32) { hS[tid] = oS[0][tid]; xS[tid] = oS[0][tid]; }
        __syncthreads();
    }
}

// ---------------- launcher ----------------
extern "C" void kernel_launch(void* const* d_in, const int* in_sizes, int n_in,
                              void* d_out, int out_size, void* d_ws, size_t ws_size,
                              hipStream_t stream) {
    const float* feat    = (const float*)d_in[0];
    const float* adj     = (const float*)d_in[1];
    const float* dis_lab = (const float*)d_in[2];
    const float* W_gat   = (const float*)d_in[3];
    const float* a_gat   = (const float*)d_in[4];
    const float* qkv_W   = (const float*)d_in[5];
    const float* qkv_b   = (const float*)d_in[6];
    const float* o_W     = (const float*)d_in[7];
    const float* o_b     = (const float*)d_in[8];
    const float* fus_W   = (const float*)d_in[9];
    const float* fus_b   = (const float*)d_in[10];
    const float* att1_W  = (const float*)d_in[11];
    const float* att1_b  = (const float*)d_in[12];
    const float* att2_W  = (const float*)d_in[13];
    const float* att2_b  = (const float*)d_in[14];
    const float* Wih     = (const float*)d_in[15];
    const float* Whh     = (const float*)d_in[16];
    const float* bih     = (const float*)d_in[17];
    const float* bhh     = (const float*)d_in[18];
    const float* out_W   = (const float*)d_in[19];
    const float* out_b   = (const float*)d_in[20];
    float* out = (float*)d_out;

    float* ws = (float*)d_ws;
    // layout (floats):
    //   hid     @ 0        (921600)  live gat..attn_part
    //   fvec    @ 921600   (28800)
    //   gvecP   @ 950400   (30720 = 24*1280)
    //   GmaxE   @ 981120   (32 u32)
    //   WhT     @ 981152   (983040 fl = 1966080 ush); part (269280) overlays after gat
    //   hsel    @ 1964192  (8448)
    //   qt      @ 1972640  (8448)
    //   qc      @ 1981088  (288)
    //   maskb   @ 1981376  (1152000 u32 = 576000 fl)
    float*  hid    = ws;
    float*  fvec   = ws + 921600;
    float*  gvecP  = ws + 950400;
    unsigned int* GmaxE = (unsigned int*)(ws + 981120);
    ushort* WhT    = (ushort*)(ws + 981152);
    float*  part   = ws + 981152;
    float*  hsel   = ws + 1964192;
    float*  qt     = ws + 1972640;
    float*  qc     = ws + 1981088;
    unsigned int* maskb = (unsigned int*)(ws + 1981376);

    adj_pack_k<<<dim3(1440), dim3(256), 0, stream>>>(adj, maskb, GmaxE);
    wh_wht_k<<<dim3(Bb * Vv * 20), dim3(256), 0, stream>>>(feat, W_gat, a_gat,
                                                           WhT, fvec, gvecP, GmaxE);
    gat_mfma_k<<<dim3(Bb * Vv * 75), dim3(256), 0, stream>>>(maskb, WhT,
                                                             fvec, gvecP, GmaxE, hid, hsel);
    attn_q_k<<<dim3(Bb), dim3(256), 0, stream>>>(hsel, qkv_W, qkv_b, qt, qc);
    attn_part_k<<<dim3(Bb * NCH), dim3(256), 0, stream>>>(hid, qt, qc, part);
    comb_head_k<<<dim3(Bb), dim3(256), 0, stream>>>(part, hsel, qkv_W, qkv_b,
                                                    o_W, o_b, fus_W, fus_b,
                                                    dis_lab, att1_W, att1_b, att2_W, att2_b,
                                                    Wih, Whh, bih, bhh, out_W, out_b, out);
}

// Round 19
// 123.502 us; speedup vs baseline: 1.4401x; 1.0095x over previous
//
#include <hip/hip_runtime.h>
#include <math.h>

#define Bb 8
#define Vv 3
#define Ss 1200
#define SgP 1280                 // padded gvec row length
#define Ff 16
#define Hh 32
#define Kk 10
#define STEPS 12
#define ROWS (Bb*Vv*Ss)          // 28800
#define L (Vv*Ss)                // 3600
#define KPAD 1280                // 8 waves * 160
#define NKB 160                  // KPAD/8 k-blocks
#define MROW 40                  // mask dwords per row (1280 bits; 38,39 zero)

typedef __attribute__((ext_vector_type(8))) short bf16x8;
typedef __attribute__((ext_vector_type(4))) float f32x4;
typedef __attribute__((ext_vector_type(4))) unsigned int u32x4;

__device__ __forceinline__ unsigned int pack_hi2(float x0, float x1) {
    return (__float_as_uint(x1) & 0xFFFF0000u) | (__float_as_uint(x0) >> 16);
}
__device__ __forceinline__ unsigned int pack_lo2(float x0, float x1) {
    float h0 = __uint_as_float(__float_as_uint(x0) & 0xFFFF0000u);
    float h1 = __uint_as_float(__float_as_uint(x1) & 0xFFFF0000u);
    return (__float_as_uint(x1 - h1) & 0xFFFF0000u) | (__float_as_uint(x0 - h0) >> 16);
}
__device__ __forceinline__ unsigned int spread4(unsigned int x) {
    x = (x | (x << 12)) & 0x000F000Fu;
    x = (x | (x << 6))  & 0x03030303u;
    x = (x | (x << 3))  & 0x11111111u;
    return x;
}
// monotone float<->uint for atomicMax
__device__ __forceinline__ unsigned int enc_f(float f) {
    unsigned int u = __float_as_uint(f);
    return (u >> 31) ? ~u : (u | 0x80000000u);
}
__device__ __forceinline__ float dec_f(unsigned int e) {
    return (e >> 31) ? __uint_as_float(e & 0x7FFFFFFFu) : __uint_as_float(~e);
}

// ---------------- Kernel P: ballot-pack adj -> 1 bit/elem (+ GmaxE init) ---------------
__global__ __launch_bounds__(256) void adj_pack_k(const float* __restrict__ adj,
                                                  unsigned int* __restrict__ maskb,
                                                  unsigned int* __restrict__ GmaxE) {
    if (blockIdx.x == 0 && threadIdx.x < Bb * Vv) GmaxE[threadIdx.x] = 0u;
    int gw = (blockIdx.x * 256 + threadIdx.x) >> 6;   // 0..5759
    int lane = threadIdx.x & 63;
    for (int row = gw; row < ROWS; row += 5760) {
        const float* ar = adj + (size_t)row * Ss;
        unsigned int* mrow = maskb + (size_t)row * MROW;
        float4 a[5];
#pragma unroll
        for (int c = 0; c < 5; ++c) {
            int base = c * 256 + lane * 4;
            a[c] = (base + 3 < Ss) ? *(const float4*)(ar + base)
                                   : make_float4(0.f, 0.f, 0.f, 0.f);
        }
#pragma unroll
        for (int c = 0; c < 5; ++c) {
            unsigned long long b0 = __ballot(a[c].x > 0.f);
            unsigned long long b1 = __ballot(a[c].y > 0.f);
            unsigned long long b2 = __ballot(a[c].z > 0.f);
            unsigned long long b3 = __ballot(a[c].w > 0.f);
            int nw = (c == 4) ? 6 : 8;
            if (lane < nw) {
                int sh = 8 * lane;
                unsigned int B0 = (unsigned int)(b0 >> sh) & 0xFFu;
                unsigned int B1 = (unsigned int)(b1 >> sh) & 0xFFu;
                unsigned int B2 = (unsigned int)(b2 >> sh) & 0xFFu;
                unsigned int B3 = (unsigned int)(b3 >> sh) & 0xFFu;
                mrow[c * 8 + lane] = spread4(B0) | (spread4(B1) << 1)
                                   | (spread4(B2) << 2) | (spread4(B3) << 3);
            }
        }
        if (lane < 2) mrow[38 + lane] = 0u;
    }
}

// ---------------- Kernel A: fused Wh compute + transpose-split + Gmax atomic ------------
__global__ __launch_bounds__(256) void wh_wht_k(const float* __restrict__ feat,
                                                const float* __restrict__ W_gat,
                                                const float* __restrict__ a_gat,
                                                ushort* __restrict__ WhT,
                                                float* __restrict__ fvec,
                                                float* __restrict__ gvecP,
                                                unsigned int* __restrict__ GmaxE) {
    int bv = blockIdx.x / 20, t = blockIdx.x % 20;
    int b = bv / Vv, v = bv - b * Vv;
    int s0 = t * 64;
    int tid = threadIdx.x;

    __shared__ float T[64][33];
    __shared__ float Wg[16][32];
    __shared__ float gred[8];
    for (int i = tid; i < 512; i += 256) Wg[i >> 5][i & 31] = W_gat[v * 512 + i];
    __syncthreads();

    int r8 = tid >> 5, h = tid & 31;
    float a1 = a_gat[v * 64 + h];
    float a2 = a_gat[v * 64 + 32 + h];
    float myg = -3.0e38f;
#pragma unroll
    for (int pass = 0; pass < 8; ++pass) {
        int s = s0 + pass * 8 + r8;
        float acc = 0.f;
        if (s < Ss) {
            const float4* fe = (const float4*)(feat + ((size_t)b * Ss + s) * Ff);
            float4 f0 = fe[0], f1 = fe[1], f2 = fe[2], f3 = fe[3];
            acc += f0.x * Wg[0][h]  + f0.y * Wg[1][h]  + f0.z * Wg[2][h]  + f0.w * Wg[3][h];
            acc += f1.x * Wg[4][h]  + f1.y * Wg[5][h]  + f1.z * Wg[6][h]  + f1.w * Wg[7][h];
            acc += f2.x * Wg[8][h]  + f2.y * Wg[9][h]  + f2.z * Wg[10][h] + f2.w * Wg[11][h];
            acc += f3.x * Wg[12][h] + f3.y * Wg[13][h] + f3.z * Wg[14][h] + f3.w * Wg[15][h];
        }
        T[pass * 8 + r8][h] = acc;
        float pf = acc * a1, pg = acc * a2;
#pragma unroll
        for (int m = 16; m >= 1; m >>= 1) {
            pf += __shfl_xor(pf, m);
            pg += __shfl_xor(pg, m);
        }
        if (h == 0) {
            if (s < Ss) { fvec[bv * Ss + s] = pf; myg = fmaxf(myg, pg); }
            gvecP[(size_t)bv * SgP + s] = (s < Ss) ? pg : 0.f;  // pad rows write 0
        }
    }
    if (h == 0) gred[r8] = myg;
    __syncthreads();
    if (tid == 0) {
        float m = gred[0];
#pragma unroll
        for (int i = 1; i < 8; ++i) m = fmaxf(m, gred[i]);
        atomicMax(&GmaxE[bv], enc_f(m));
    }

    int hh = tid >> 3, c = tid & 7;       // 32 h x 8 kb-in-block
    int kb = t * 8 + c;
    unsigned int hb[4], lb[4];
#pragma unroll
    for (int j = 0; j < 4; ++j) {
        float e0 = T[c * 8 + 2 * j][hh], e1 = T[c * 8 + 2 * j + 1][hh];
        hb[j] = pack_hi2(e0, e1);
        lb[j] = pack_lo2(e0, e1);
    }
    size_t base = (((size_t)bv * NKB + kb) * 2) * 256 + hh * 8;   // ushort index
    *(uint4*)(WhT + base)       = make_uint4(hb[0], hb[1], hb[2], hb[3]);  // hi plane
    *(uint4*)(WhT + base + 256) = make_uint4(lb[0], lb[1], lb[2], lb[3]);  // lo plane
}

// ---------------- Kernel B: MFMA GAT attention, 8-way split-K (TLP x2) ------------------
// 512 thr = 8 waves; block = 16 rows; wave wk covers k in [wk*160, wk*160+160): 5 steps.
__global__ __launch_bounds__(512) void gat_mfma_k(const unsigned int* __restrict__ maskb,
                                                  const ushort* __restrict__ WhT,
                                                  const float* __restrict__ fvec,
                                                  const float* __restrict__ gvecP,
                                                  const unsigned int* __restrict__ GmaxE,
                                                  float* __restrict__ hid,
                                                  float* __restrict__ hsel) {
    int blk = blockIdx.x;
    int bv = blk / 75, tb = blk % 75;
    int wk = threadIdx.x >> 6, lane = threadIdx.x & 63;   // wk in [0,8)
    int rowbase = tb * 16;
    int lr = lane & 15, kg = lane >> 4;
    int b = bv / Vv, v = bv - b * Vv;

    int ar = rowbase + lr;                // always < 1200
    const float* g_b = gvecP + (size_t)bv * SgP;
    float fr = fvec[bv * Ss + ar];
    float M = fr + dec_f(GmaxE[bv]);
    float Mr = fmaxf(M, 0.2f * M);        // leaky_relu of bound >= true row max

    // preload this wave's mask window: 5 dwords (160 bits)
    const unsigned int* mrow = maskb + (size_t)(bv * Ss + ar) * MROW + wk * 5;
    unsigned int mw[5];
#pragma unroll
    for (int i = 0; i < 5; ++i) mw[i] = mrow[i];

    f32x4 acc0 = {0.f, 0.f, 0.f, 0.f}, acc1 = {0.f, 0.f, 0.f, 0.f};
    float psum = 0.f;
    const ushort* Wbv = WhT + ((size_t)bv * NKB) * 512;

    int kst = wk * 160;
#pragma unroll
    for (int s = 0; s < 5; ++s) {
        int t0 = kst + s * 32 + kg * 8;   // <= 1272; all buffers padded to 1280
        int kb = t0 >> 3;
        unsigned int mb = (mw[s] >> (kg * 8)) & 0xFFu;

        const ushort* Bp = Wbv + (size_t)kb * 512 + lr * 8;
        bf16x8 bh0 = *(const bf16x8*)(Bp);            // hi, h = lr
        bf16x8 bh1 = *(const bf16x8*)(Bp + 128);      // hi, h = 16+lr
        bf16x8 bl0 = *(const bf16x8*)(Bp + 256);      // lo, h = lr
        bf16x8 bl1 = *(const bf16x8*)(Bp + 384);      // lo, h = 16+lr

        float4 gA = *(const float4*)(g_b + t0);
        float4 gB = *(const float4*)(g_b + t0 + 4);
        float gv8[8] = {gA.x, gA.y, gA.z, gA.w, gB.x, gB.y, gB.z, gB.w};
        float p[8];
#pragma unroll
        for (int j = 0; j < 8; ++j) {
            float e = fr + gv8[j];
            e = fmaxf(e, 0.2f * e);
            float pe = __expf(e - Mr);
            p[j] = ((mb >> j) & 1u) ? pe : 0.f;
            psum += p[j];
        }
        unsigned int hbp[4], lbp[4];
#pragma unroll
        for (int j = 0; j < 4; ++j) {
            hbp[j] = pack_hi2(p[2 * j], p[2 * j + 1]);
            lbp[j] = pack_lo2(p[2 * j], p[2 * j + 1]);
        }
        bf16x8 ah = __builtin_bit_cast(bf16x8, (u32x4){hbp[0], hbp[1], hbp[2], hbp[3]});
        bf16x8 al = __builtin_bit_cast(bf16x8, (u32x4){lbp[0], lbp[1], lbp[2], lbp[3]});
        acc0 = __builtin_amdgcn_mfma_f32_16x16x32_bf16(ah, bh0, acc0, 0, 0, 0);
        acc0 = __builtin_amdgcn_mfma_f32_16x16x32_bf16(ah, bl0, acc0, 0, 0, 0);
        acc0 = __builtin_amdgcn_mfma_f32_16x16x32_bf16(al, bh0, acc0, 0, 0, 0);
        acc1 = __builtin_amdgcn_mfma_f32_16x16x32_bf16(ah, bh1, acc1, 0, 0, 0);
        acc1 = __builtin_amdgcn_mfma_f32_16x16x32_bf16(ah, bl1, acc1, 0, 0, 0);
        acc1 = __builtin_amdgcn_mfma_f32_16x16x32_bf16(al, bh1, acc1, 0, 0, 0);
    }

    // row-sum within wave (over kg), then LDS combine over the 8 K-waves
    psum += __shfl_xor(psum, 16);
    psum += __shfl_xor(psum, 32);

    __shared__ float accS[8][2][16][17];
    __shared__ float psS[8][16];
#pragma unroll
    for (int j = 0; j < 4; ++j) {
        accS[wk][0][kg * 4 + j][lr] = acc0[j];
        accS[wk][1][kg * 4 + j][lr] = acc1[j];
    }
    if (lane < 16) psS[wk][lr] = psum;
    __syncthreads();
    if (threadIdx.x < 16) {
        float t = 0.f;
#pragma unroll
        for (int w = 0; w < 8; ++w) t += psS[w][threadIdx.x];
        psS[0][threadIdx.x] = t;
    }
    __syncthreads();

    bool qb = (tb == 50);                 // rows 800..815
    {
        int idx = threadIdx.x;            // 512 threads cover 512 outputs
        int r = idx >> 5, col = idx & 31, tt = col >> 4, c = col & 15;
        float a = 0.f;
#pragma unroll
        for (int w = 0; w < 8; ++w) a += accS[w][tt][r][c];
        float rr = a / psS[0][r];
        float hv = (rr > 0.f) ? rr : expm1f(rr);
        hid[((size_t)bv * Ss + rowbase + r) * 32 + col] = hv;
        if (qb && r < 11) hsel[(((size_t)b * Vv + v) * 11 + r) * 32 + col] = hv;
    }
}

// ---------------- Kernel Q: per-batch query precompute (q, qt, qc) in hid-space ---------
__global__ __launch_bounds__(256) void attn_q_k(const float* __restrict__ hsel,
                                                const float* __restrict__ qkv_W,
                                                const float* __restrict__ qkv_b,
                                                float* __restrict__ qt,
                                                float* __restrict__ qc) {
    int b = blockIdx.x;
    int tid = threadIdx.x;
    __shared__ float hq[33][33];
    __shared__ float W1[32][33];
    __shared__ float W2[32][33];
    __shared__ float qS[33][33];

    for (int idx = tid; idx < 33 * 32; idx += 256) {
        int q = idx >> 5, i = idx & 31;
        int si = q / 3, v = q - si * 3;
        hq[q][i] = hsel[(((size_t)b * Vv + v) * 11 + si) * 32 + i];
    }
    for (int idx = tid; idx < 1024; idx += 256) {
        int i = idx >> 5, j = idx & 31;
        W1[i][j] = qkv_W[i * 96 + j];
        W2[i][j] = qkv_W[i * 96 + 32 + j];
    }
    __syncthreads();
    for (int idx = tid; idx < 33 * 32; idx += 256) {
        int q = idx >> 5, j = idx & 31;
        float a = qkv_b[j];
#pragma unroll
        for (int i = 0; i < 32; ++i) a += hq[q][i] * W1[i][j];
        qS[q][j] = a;
    }
    __syncthreads();
    for (int idx = tid; idx < 33 * 32; idx += 256) {
        int q = idx >> 5, i = idx & 31;
        float a = 0.f;
#pragma unroll
        for (int j = 0; j < 32; ++j) a += qS[q][j] * W2[i][j];
        qt[(size_t)b * 33 * 32 + q * 32 + i] = a;
    }
    if (tid < 33) {
        float a = 0.f;
        for (int j = 0; j < 32; ++j) a += qS[tid][j] * qkv_b[32 + j];
        qc[b * 33 + tid] = a;
    }
}

// ---------------- Kernel D1: split-K attention partials, hid-space ----------------
#define CH 120
#define NCH 30
#define PREC 34
__global__ __launch_bounds__(256) void attn_part_k(const float* __restrict__ hid,
                                                   const float* __restrict__ qt,
                                                   const float* __restrict__ qc,
                                                   float* __restrict__ part) {
    int blk = blockIdx.x;                 // b*NCH + ch
    int b = blk / NCH, ch = blk % NCH;
    int k0 = ch * CH;
    int tid = threadIdx.x;
    const float inv = 0.1767766952966369f; // 1/sqrt(32)

    __shared__ float hC[CH][33];
    __shared__ float qtS[33][33];
    __shared__ float qcS[33];
    __shared__ float lS[33][124];
    __shared__ float mS[33], lsS[33];

    for (int idx = tid; idx < CH * 32; idx += 256) {
        int r = idx >> 5, i = idx & 31;
        hC[r][i] = hid[((size_t)b * L + k0 + r) * 32 + i];
    }
    for (int idx = tid; idx < 33 * 32; idx += 256) {
        int q = idx >> 5, i = idx & 31;
        qtS[q][i] = qt[(size_t)b * 33 * 32 + q * 32 + i];
    }
    if (tid < 33) qcS[tid] = qc[b * 33 + tid];
    __syncthreads();

    for (int idx = tid; idx < 33 * CH; idx += 256) {
        int q = idx / CH, m = idx - q * CH;
        float d = 0.f;
#pragma unroll
        for (int i = 0; i < 32; ++i) d += qtS[q][i] * hC[m][i];
        lS[q][m] = (d + qcS[q]) * inv;
    }
    __syncthreads();

    int q4 = tid >> 2, j4 = tid & 3;
    if (q4 < 33) {
        float m = -3.0e38f;
        for (int k = j4; k < CH; k += 4) m = fmaxf(m, lS[q4][k]);
        m = fmaxf(m, __shfl_xor(m, 1));
        m = fmaxf(m, __shfl_xor(m, 2));
        float ssum = 0.f;
        for (int k = j4; k < CH; k += 4) {
            float p = __expf(lS[q4][k] - m);
            lS[q4][k] = p;
            ssum += p;
        }
        ssum += __shfl_xor(ssum, 1);
        ssum += __shfl_xor(ssum, 2);
        if (j4 == 0) { mS[q4] = m; lsS[q4] = ssum; }
    }
    __syncthreads();

    float* po = part + ((size_t)b * NCH + ch) * (33 * PREC);
    for (int idx = tid; idx < 33 * 32; idx += 256) {
        int q = idx >> 5, hh = idx & 31;
        float a = 0.f;
        for (int k = 0; k < CH; k += 4) {
            float4 p4 = *(const float4*)&lS[q][k];
            a += p4.x * hC[k][hh] + p4.y * hC[k+1][hh] + p4.z * hC[k+2][hh] + p4.w * hC[k+3][hh];
        }
        po[q * PREC + hh] = a;
    }
    if (tid < 33) { po[tid * PREC + 32] = mS[tid]; po[tid * PREC + 33] = lsS[tid]; }
}

// ---------------- Kernel D2+E: combine + Wv + o-proj + fuse + gate + scores + GRU -------
__global__ __launch_bounds__(256) void comb_head_k(const float* __restrict__ part,
                                                   const float* __restrict__ hsel,
                                                   const float* __restrict__ qkv_W,
                                                   const float* __restrict__ qkv_b,
                                                   const float* __restrict__ o_W,
                                                   const float* __restrict__ o_b,
                                                   const float* __restrict__ fus_W,
                                                   const float* __restrict__ fus_b,
                                                   const float* __restrict__ dis_lab,
                                                   const float* __restrict__ att1_W,
                                                   const float* __restrict__ att1_b,
                                                   const float* __restrict__ att2_W,
                                                   const float* __restrict__ att2_b,
                                                   const float* __restrict__ Wih,
                                                   const float* __restrict__ Whh,
                                                   const float* __restrict__ bih,
                                                   const float* __restrict__ bhh,
                                                   const float* __restrict__ out_W,
                                                   const float* __restrict__ out_b,
                                                   float* __restrict__ out) {
    int b = blockIdx.x;
    int tid = threadIdx.x;
    __shared__ float RS[33][NCH];
    __shared__ float LSs[33];
    __shared__ float oS[33][33];
    __shared__ float vS[33][33];
    __shared__ float hfS[33][33];
    __shared__ float hfgS[33][32];
    __shared__ float lab[11][32];
    __shared__ float a1T[32][68];
    __shared__ float WihT[3][32][36];
    __shared__ float WhhT[3][32][36];
    __shared__ float sc[12];
    __shared__ float xS[32], hS[32];

    const float* pb = part + (size_t)b * NCH * (33 * PREC);

    if (tid < 33) {
        float M = -3.0e38f;
        for (int c = 0; c < NCH; ++c) M = fmaxf(M, pb[c * 33 * PREC + tid * PREC + 32]);
        float Lt = 0.f;
        for (int c = 0; c < NCH; ++c) {
            float w = __expf(pb[c * 33 * PREC + tid * PREC + 32] - M);
            RS[tid][c] = w;
            Lt += w * pb[c * 33 * PREC + tid * PREC + 33];
        }
        LSs[tid] = Lt;
    }
    __syncthreads();

    for (int idx = tid; idx < 33 * 32; idx += 256) {
        int q = idx >> 5, hh = idx & 31;
        float a = 0.f;
        for (int c = 0; c < NCH; ++c) a += RS[q][c] * pb[c * 33 * PREC + q * PREC + hh];
        oS[q][hh] = a / LSs[q];           // sa in hid-space
    }
    __syncthreads();
    for (int idx = tid; idx < 33 * 32; idx += 256) {
        int q = idx >> 5, j = idx & 31;
        float a = qkv_b[64 + j];
#pragma unroll
        for (int i = 0; i < 32; ++i) a += oS[q][i] * qkv_W[i * 96 + 64 + j];
        vS[q][j] = a;                     // sa in v-space
    }
    __syncthreads();
    for (int idx = tid; idx < 33 * 32; idx += 256) {
        int q = idx >> 5, hh = idx & 31;
        int si = q / 3, v = q - si * 3;
        float o = o_b[hh];
#pragma unroll
        for (int i = 0; i < 32; ++i) o += vS[q][i] * o_W[i * 32 + hh];
        float x = hsel[(((size_t)b * Vv + v) * 11 + si) * Hh + hh];
        hfS[q][hh] = 0.8f * o + 0.2f * x;
    }
    __syncthreads();
    for (int idx = tid; idx < 33 * 32; idx += 256) {
        int q = idx >> 5, hh = idx & 31;
        float gacc = fus_b[hh];
#pragma unroll
        for (int i = 0; i < 32; ++i) gacc += hfS[q][i] * fus_W[i * 32 + hh];
        float gate = 1.f / (1.f + __expf(-gacc));
        hfgS[q][hh] = gate * hfS[q][hh];
    }
    __syncthreads();

    // ================= head phase =================
    for (int i = tid; i < 352; i += 256) {
        int k = i >> 5, hh = i & 31;
        lab[k][hh] = hfgS[k * 3 + 0][hh] + hfgS[k * 3 + 1][hh] + hfgS[k * 3 + 2][hh];
    }
    for (int idx = tid; idx < 2048; idx += 256) {
        int i = idx >> 5, jj = idx & 31;
        a1T[jj][i] = att1_W[idx];
    }
    for (int idx = tid; idx < 3072; idx += 256) {
        int i = idx / 96, col = idx - i * 96;
        int g = col >> 5, jj = col & 31;
        WihT[g][jj][i] = Wih[idx];
        WhhT[g][jj][i] = Whh[idx];
    }
    __syncthreads();

    int j = tid & 31, half = (tid >> 5) & 1;
    if (tid < 64) {
        float a2w = att2_W[j];
        float a1b = att1_b[j];
        float a2b = att2_b[0];
#pragma unroll
        for (int kk = 0; kk < 5; ++kk) {
            int k = 2 * kk + half;
            float t1 = a1b;
#pragma unroll
            for (int c = 0; c < 8; ++c) {
                float4 lb4 = *(const float4*)&lab[k][c * 4];
                float4 w4  = *(const float4*)&a1T[j][c * 4];
                t1 += lb4.x * w4.x + lb4.y * w4.y + lb4.z * w4.z + lb4.w * w4.w;
            }
#pragma unroll
            for (int c = 0; c < 8; ++c) {
                float4 lb4 = *(const float4*)&lab[10][c * 4];
                float4 w4  = *(const float4*)&a1T[j][32 + c * 4];
                t1 += lb4.x * w4.x + lb4.y * w4.y + lb4.z * w4.z + lb4.w * w4.w;
            }
            float val = fmaxf(t1, 0.f) * a2w;
#pragma unroll
            for (int mm = 16; mm >= 1; mm >>= 1) val += __shfl_xor(val, mm);
            if (j == 0) sc[k] = (val + a2b) * dis_lab[b * Kk + k];
        }
    }
    __syncthreads();
    if (tid == 0) {
        float mx = sc[0];
        for (int k = 1; k < 10; ++k) mx = fmaxf(mx, sc[k]);
        float sm = 0.f;
        for (int k = 0; k < 10; ++k) { sc[k] = __expf(sc[k] - mx); sm += sc[k]; }
        for (int k = 0; k < 10; ++k) sc[k] /= sm;
    }
    __syncthreads();
    if (tid < 32) {
        float c = 0.f;
        for (int k = 0; k < 10; ++k) c += sc[k] * lab[k][tid];
        xS[tid] = c;
        hS[tid] = lab[10][tid];
    }
    __syncthreads();

    float b_ir = bih[j], b_iz = bih[32 + j], b_in = bih[64 + j];
    float b_hr = bhh[j], b_hz = bhh[32 + j], b_hn = bhh[64 + j];
    float ow = out_W[j], ob = out_b[0];
    int i0 = half * 16;

    for (int t = 0; t < STEPS; ++t) {
        if (tid < 64) {
            float gi_r = 0.f, gi_z = 0.f, gi_n = 0.f;
            float gh_r = 0.f, gh_z = 0.f, gh_n = 0.f;
#pragma unroll
            for (int c = 0; c < 4; ++c) {
                float4 x4 = *(const float4*)&xS[i0 + c * 4];
                float4 h4 = *(const float4*)&hS[i0 + c * 4];
                float4 wr = *(const float4*)&WihT[0][j][i0 + c * 4];
                float4 wz = *(const float4*)&WihT[1][j][i0 + c * 4];
                float4 wn = *(const float4*)&WihT[2][j][i0 + c * 4];
                float4 ur = *(const float4*)&WhhT[0][j][i0 + c * 4];
                float4 uz = *(const float4*)&WhhT[1][j][i0 + c * 4];
                float4 un = *(const float4*)&WhhT[2][j][i0 + c * 4];
                gi_r += x4.x * wr.x + x4.y * wr.y + x4.z * wr.z + x4.w * wr.w;
                gi_z += x4.x * wz.x + x4.y * wz.y + x4.z * wz.z + x4.w * wz.w;
                gi_n += x4.x * wn.x + x4.y * wn.y + x4.z * wn.z + x4.w * wn.w;
                gh_r += h4.x * ur.x + h4.y * ur.y + h4.z * ur.z + h4.w * ur.w;
                gh_z += h4.x * uz.x + h4.y * uz.y + h4.z * uz.z + h4.w * uz.w;
                gh_n += h4.x * un.x + h4.y * un.y + h4.z * un.z + h4.w * un.w;
            }
            gi_r += __shfl_xor(gi_r, 32); gi_z += __shfl_xor(gi_z, 32); gi_n += __shfl_xor(gi_n, 32);
            gh_r += __shfl_xor(gh_r, 32); gh_z += __shfl_xor(gh_z, 32); gh_n += __shfl_xor(gh_n, 32);

            float hprev = hS[j];
            float r = 1.f / (1.f + __expf(-(gi_r + b_ir + gh_r + b_hr)));
            float z = 1.f / (1.f + __expf(-(gi_z + b_iz + gh_z + b_hz)));
            float n = tanhf(gi_n + b_in + r * (gh_n + b_hn));
            float hnew = (1.f - z) * n + z * hprev;

            float outp = hnew * ow;
#pragma unroll
            for (int mm = 16; mm >= 1; mm >>= 1) outp += __shfl_xor(outp, mm);
            if (tid == 0) out[b * STEPS + t] = outp + ob;
            if (tid < 32) oS[0][j] = hnew;     // stash (oS free now)
        }
        __syncthreads();
        if (tid < 32) { hS[tid] = oS[0][tid]; xS[tid] = oS[0][tid]; }
        __syncthreads();
    }
}

// ---------------- launcher ----------------
extern "C" void kernel_launch(void* const* d_in, const int* in_sizes, int n_in,
                              void* d_out, int out_size, void* d_ws, size_t ws_size,
                              hipStream_t stream) {
    const float* feat    = (const float*)d_in[0];
    const float* adj     = (const float*)d_in[1];
    const float* dis_lab = (const float*)d_in[2];
    const float* W_gat   = (const float*)d_in[3];
    const float* a_gat   = (const float*)d_in[4];
    const float* qkv_W   = (const float*)d_in[5];
    const float* qkv_b   = (const float*)d_in[6];
    const float* o_W     = (const float*)d_in[7];
    const float* o_b     = (const float*)d_in[8];
    const float* fus_W   = (const float*)d_in[9];
    const float* fus_b   = (const float*)d_in[10];
    const float* att1_W  = (const float*)d_in[11];
    const float* att1_b  = (const float*)d_in[12];
    const float* att2_W  = (const float*)d_in[13];
    const float* att2_b  = (const float*)d_in[14];
    const float* Wih     = (const float*)d_in[15];
    const float* Whh     = (const float*)d_in[16];
    const float* bih     = (const float*)d_in[17];
    const float* bhh     = (const float*)d_in[18];
    const float* out_W   = (const float*)d_in[19];
    const float* out_b   = (const float*)d_in[20];
    float* out = (float*)d_out;

    float* ws = (float*)d_ws;
    // layout (floats):
    //   hid     @ 0        (921600)  live gat..attn_part
    //   fvec    @ 921600   (28800)
    //   gvecP   @ 950400   (30720 = 24*1280)
    //   GmaxE   @ 981120   (32 u32)
    //   WhT     @ 981152   (983040 fl = 1966080 ush); part (269280) overlays after gat
    //   hsel    @ 1964192  (8448)
    //   qt      @ 1972640  (8448)
    //   qc      @ 1981088  (288)
    //   maskb   @ 1981376  (1152000 u32 = 576000 fl)
    float*  hid    = ws;
    float*  fvec   = ws + 921600;
    float*  gvecP  = ws + 950400;
    unsigned int* GmaxE = (unsigned int*)(ws + 981120);
    ushort* WhT    = (ushort*)(ws + 981152);
    float*  part   = ws + 981152;
    float*  hsel   = ws + 1964192;
    float*  qt     = ws + 1972640;
    float*  qc     = ws + 1981088;
    unsigned int* maskb = (unsigned int*)(ws + 1981376);

    adj_pack_k<<<dim3(1440), dim3(256), 0, stream>>>(adj, maskb, GmaxE);
    wh_wht_k<<<dim3(Bb * Vv * 20), dim3(256), 0, stream>>>(feat, W_gat, a_gat,
                                                           WhT, fvec, gvecP, GmaxE);
    gat_mfma_k<<<dim3(Bb * Vv * 75), dim3(512), 0, stream>>>(maskb, WhT,
                                                             fvec, gvecP, GmaxE, hid, hsel);
    attn_q_k<<<dim3(Bb), dim3(256), 0, stream>>>(hsel, qkv_W, qkv_b, qt, qc);
    attn_part_k<<<dim3(Bb * NCH), dim3(256), 0, stream>>>(hid, qt, qc, part);
    comb_head_k<<<dim3(Bb), dim3(256), 0, stream>>>(part, hsel, qkv_W, qkv_b,
                                                    o_W, o_b, fus_W, fus_b,
                                                    dis_lab, att1_W, att1_b, att2_W, att2_b,
                                                    Wih, Whh, bih, bhh, out_W, out_b, out);
}